// Round 3
// baseline (1320.610 us; speedup 1.0000x reference)
//
#include <hip/hip_runtime.h>
#include <math.h>

#define NB 4
#define LB 16384
#define CB 256
#define HB 8
#define DB 32
#define NLB (NB * LB)
#define SPLITS 32          // per-n splits of L for the KV reduction
#define SPLIT_ROWS (LB / SPLITS)  // 512

// ---------------------------------------------------------------------------
// Shared fp32 GEMM core: 64x256 output tile per 256-thread block, BK=16.
// A row-major [*,256] (caller points at the block's 64-row panel), B row-major
// [256,256]. Thread (tx,ty) owns rows ty*8..+7, cols tx+32*j. Accumulates.
// ---------------------------------------------------------------------------
__device__ __forceinline__ void gemm_acc(const float* __restrict__ A,
                                         const float* __restrict__ B,
                                         float acc[8][8],
                                         float* __restrict__ AsT,  // [16][68]
                                         float* __restrict__ Bs,   // [16][256]
                                         int tx, int ty) {
  const int t = threadIdx.x;
  for (int ks = 0; ks < 16; ++ks) {
    const int k0 = ks * 16;
    __syncthreads();
    {  // stage A 64x16 transposed (pad 68 breaks bank conflicts)
      int row = t >> 2, q = t & 3;
      float4 av = *(const float4*)&A[row * 256 + k0 + q * 4];
      AsT[(q * 4 + 0) * 68 + row] = av.x;
      AsT[(q * 4 + 1) * 68 + row] = av.y;
      AsT[(q * 4 + 2) * 68 + row] = av.z;
      AsT[(q * 4 + 3) * 68 + row] = av.w;
    }
    #pragma unroll
    for (int r = 0; r < 4; ++r) {  // stage B 16x256
      int fi = t + 256 * r;
      int brow = fi >> 6, c4 = fi & 63;
      *(float4*)&Bs[brow * 256 + c4 * 4] =
          *(const float4*)&B[(k0 + brow) * 256 + c4 * 4];
    }
    __syncthreads();
    #pragma unroll
    for (int kk = 0; kk < 16; ++kk) {
      float4 a01 = *(const float4*)&AsT[kk * 68 + ty * 8];
      float4 a23 = *(const float4*)&AsT[kk * 68 + ty * 8 + 4];
      float a[8] = {a01.x, a01.y, a01.z, a01.w, a23.x, a23.y, a23.z, a23.w};
      float b[8];
      #pragma unroll
      for (int j = 0; j < 8; ++j) b[j] = Bs[kk * 256 + tx + 32 * j];
      #pragma unroll
      for (int i = 0; i < 8; ++i)
        #pragma unroll
        for (int j = 0; j < 8; ++j) acc[i][j] = fmaf(a[i], b[j], acc[i][j]);
    }
  }
}

// LayerNorm epilogue over full 256-wide rows. Row values live in the 32
// tx-lanes of one ty group; butterfly masks <32 stay inside that group.
template <bool RESID>
__device__ __forceinline__ void ln_write(float acc[8][8],
                                         const float* __restrict__ g,
                                         const float* __restrict__ bb,
                                         const float* __restrict__ resid,
                                         float* __restrict__ out, int row0,
                                         int tx, int ty) {
  #pragma unroll
  for (int i = 0; i < 8; ++i) {
    float s1 = 0.f, s2 = 0.f;
    #pragma unroll
    for (int j = 0; j < 8; ++j) {
      float v = acc[i][j];
      s1 += v;
      s2 += v * v;
    }
    #pragma unroll
    for (int m = 16; m >= 1; m >>= 1) {
      s1 += __shfl_xor(s1, m);
      s2 += __shfl_xor(s2, m);
    }
    float mu = s1 * (1.f / 256.f);
    float var = s2 * (1.f / 256.f) - mu * mu;
    float rn = rsqrtf(var + 1e-5f);
    int grow = row0 + ty * 8 + i;
    #pragma unroll
    for (int j = 0; j < 8; ++j) {
      int c = tx + 32 * j;
      float v = (acc[i][j] - mu) * rn * g[c] + bb[c];
      if (RESID) v += resid[(size_t)grow * 256 + c];
      out[(size_t)grow * 256 + c] = v;
    }
  }
}

// 1) out = A @ W (+ optional phi = elu+1). Rows are local to the A/out base.
__global__ __launch_bounds__(256) void proj_kernel(const float* __restrict__ A,
                                                   const float* __restrict__ W,
                                                   float* __restrict__ out,
                                                   int do_phi) {
  __shared__ float AsT[16 * 68];
  __shared__ float Bs[16 * 256];
  const int row0 = blockIdx.x * 64;
  const int tx = threadIdx.x & 31, ty = threadIdx.x >> 5;
  float acc[8][8] = {};
  gemm_acc(A + (size_t)row0 * 256, W, acc, AsT, Bs, tx, ty);
  #pragma unroll
  for (int i = 0; i < 8; ++i) {
    int grow = row0 + ty * 8 + i;
    #pragma unroll
    for (int j = 0; j < 8; ++j) {
      int c = tx + 32 * j;
      float v = acc[i][j];
      if (do_phi) v = (v > 0.f) ? v + 1.f : __expf(v);  // elu + 1
      out[(size_t)grow * 256 + c] = v;
    }
  }
}

// 2) Per-n partial KV = K^T V and Ksum. K,V bases cover this n's 16384 rows.
//    grid = (H=8, SPLITS=32); each block fully writes its 1056-float record.
__global__ __launch_bounds__(256) void kv_partial_kernel(
    const float* __restrict__ K, const float* __restrict__ V,
    float* __restrict__ Pp) {
  __shared__ float Ksh[64][32];
  __shared__ float Vsh[64][32];
  const int h = blockIdx.x;
  const int l0 = blockIdx.y * SPLIT_ROWS;
  const int t = threadIdx.x;
  const int d = t >> 3, vg = t & 7;
  float acc[4] = {0.f, 0.f, 0.f, 0.f};
  float ksacc = 0.f;
  for (int tile = 0; tile < SPLIT_ROWS / 64; ++tile) {
    __syncthreads();
    #pragma unroll
    for (int r = 0; r < 2; ++r) {
      int fi = t + 256 * r;
      int rr = fi >> 3, c4 = fi & 7;
      size_t base = (size_t)(l0 + tile * 64 + rr) * 256 + h * 32 + c4 * 4;
      *(float4*)&Ksh[rr][c4 * 4] = *(const float4*)&K[base];
      *(float4*)&Vsh[rr][c4 * 4] = *(const float4*)&V[base];
    }
    __syncthreads();
    for (int r = 0; r < 64; ++r) {
      float kv = Ksh[r][d];
      if (vg == 0) ksacc += kv;
      #pragma unroll
      for (int q = 0; q < 4; ++q) acc[q] = fmaf(kv, Vsh[r][vg * 4 + q], acc[q]);
    }
  }
  float* rec = Pp + (size_t)(blockIdx.y * HB + h) * 1056;
  #pragma unroll
  for (int q = 0; q < 4; ++q) rec[d * 32 + vg * 4 + q] = acc[q];
  if (vg == 0) rec[1024 + d] = ksacc;
}

// 2b) Reduce SPLITS records for one n. grid = H; KVn/KSn pre-offset to n.
__global__ __launch_bounds__(256) void kv_final_kernel(
    const float* __restrict__ Pp, float* __restrict__ KVn,
    float* __restrict__ KSn) {
  const int h = blockIdx.x;
  const int t = threadIdx.x;
  for (int i = t; i < 1056; i += 256) {
    float s = 0.f;
    for (int sp = 0; sp < SPLITS; ++sp) s += Pp[(size_t)(sp * HB + h) * 1056 + i];
    if (i < 1024)
      KVn[(size_t)h * 1024 + i] = s;
    else
      KSn[h * 32 + (i - 1024)] = s;
  }
}

// 3) msg[l,c] = (Q_h . KV_h[:,c&31]) / (Q_h . Ksum_h + eps); /L and *L cancel.
//    IN-PLACE on the Q panel (rows staged in LDS first). 32 rows/block.
__global__ __launch_bounds__(256) void msg_kernel(float* __restrict__ QM,
                                                  const float* __restrict__ KV,
                                                  const float* __restrict__ KS) {
  __shared__ float Qs[32][256];
  __shared__ float kvs[8][32][32];
  __shared__ float ks[8][32];
  __shared__ float zs[32][8];
  const int t = threadIdx.x;
  const int row0 = blockIdx.x * 32;
  const int n = row0 >> 14;  // L = 16384
  #pragma unroll
  for (int r = 0; r < 8; ++r) {
    int fi = t + 256 * r;
    int rr = fi >> 6, c4 = fi & 63;
    *(float4*)&Qs[rr][c4 * 4] =
        *(const float4*)&QM[(size_t)(row0 + rr) * 256 + c4 * 4];
  }
  const float* KVn = KV + (size_t)n * (HB * DB * DB);
  #pragma unroll
  for (int r = 0; r < 8; ++r) {
    int fi = t + 256 * r;
    ((float4*)kvs)[fi] = ((const float4*)KVn)[fi];
  }
  ((float*)ks)[t] = KS[n * 256 + t];
  __syncthreads();
  {
    int l = t >> 3, h = t & 7;
    float dsum = 0.f;
    #pragma unroll
    for (int dd = 0; dd < 32; ++dd)
      dsum = fmaf(Qs[l][h * 32 + dd], ks[h][dd], dsum);
    zs[l][h] = 1.0f / (dsum + 1e-6f);
  }
  __syncthreads();
  const int c = t, h = c >> 5, v = c & 31;
  for (int l = 0; l < 32; ++l) {
    float s = 0.f;
    #pragma unroll
    for (int dd = 0; dd < 32; ++dd)
      s = fmaf(Qs[l][h * 32 + dd], kvs[h][dd][v], s);
    QM[(size_t)(row0 + l) * 256 + c] = s * zs[l][h];
  }
}

// 4) m1 = LayerNorm(msg @ Wm, g1, b1)    (rows local to M/m1 bases)
__global__ __launch_bounds__(256) void att_ln_kernel(
    const float* __restrict__ M, const float* __restrict__ Wm,
    const float* __restrict__ g1, const float* __restrict__ b1,
    float* __restrict__ m1) {
  __shared__ float AsT[16 * 68];
  __shared__ float Bs[16 * 256];
  const int row0 = blockIdx.x * 64;
  const int tx = threadIdx.x & 31, ty = threadIdx.x >> 5;
  float acc[8][8] = {};
  gemm_acc(M + (size_t)row0 * 256, Wm, acc, AsT, Bs, tx, ty);
  ln_write<false>(acc, g1, b1, nullptr, m1, row0, tx, ty);
}

// 5) h = relu(x @ W1[:256] + m1 @ W1[256:])
__global__ __launch_bounds__(256) void mlp1_kernel(const float* __restrict__ x,
                                                   const float* __restrict__ m1,
                                                   const float* __restrict__ W1,
                                                   float* __restrict__ hbuf) {
  __shared__ float AsT[16 * 68];
  __shared__ float Bs[16 * 256];
  const int row0 = blockIdx.x * 64;
  const int tx = threadIdx.x & 31, ty = threadIdx.x >> 5;
  float acc[8][8] = {};
  gemm_acc(x + (size_t)row0 * 256, W1, acc, AsT, Bs, tx, ty);
  gemm_acc(m1 + (size_t)row0 * 256, W1 + 256 * 256, acc, AsT, Bs, tx, ty);
  #pragma unroll
  for (int i = 0; i < 8; ++i) {
    int grow = row0 + ty * 8 + i;
    #pragma unroll
    for (int j = 0; j < 8; ++j) {
      int c = tx + 32 * j;
      hbuf[(size_t)grow * 256 + c] = fmaxf(acc[i][j], 0.f);
    }
  }
}

// 6) out = x + LayerNorm(h @ W2, g2, b2)
__global__ __launch_bounds__(256) void mlp2_kernel(
    const float* __restrict__ hbuf, const float* __restrict__ W2,
    const float* __restrict__ g2, const float* __restrict__ b2,
    const float* __restrict__ x, float* __restrict__ out) {
  __shared__ float AsT[16 * 68];
  __shared__ float Bs[16 * 256];
  const int row0 = blockIdx.x * 64;
  const int tx = threadIdx.x & 31, ty = threadIdx.x >> 5;
  float acc[8][8] = {};
  gemm_acc(hbuf + (size_t)row0 * 256, W2, acc, AsT, Bs, tx, ty);
  ln_write<true>(acc, g2, b2, x, out, row0, tx, ty);
}

// ---------------------------------------------------------------------------
// Workspace budget — hard cap well under 64 MiB (prior rounds' fault suspect):
//   bufA 16 MiB + bufB 16 MiB + Pp 1.06 MB + KV 128 KB + KS 4 KB  ~= 33.4 MB.
// d_out doubles as scratch: V panel -> Q panel -> msg (in-place) -> final out.
// Every ws/d_out word is written before it is read (0xAA re-poison safe).
// No atomics, no memsets: deterministic under graph replay.
// ---------------------------------------------------------------------------
extern "C" void kernel_launch(void* const* d_in, const int* in_sizes, int n_in,
                              void* d_out, int out_size, void* d_ws,
                              size_t ws_size, hipStream_t stream) {
  const float* x = (const float*)d_in[0];
  const float* Wq = (const float*)d_in[1];
  const float* Wk = (const float*)d_in[2];
  const float* Wv = (const float*)d_in[3];
  const float* Wm = (const float*)d_in[4];
  const float* W1 = (const float*)d_in[5];
  const float* W2 = (const float*)d_in[6];
  const float* g1 = (const float*)d_in[7];
  const float* b1 = (const float*)d_in[8];
  const float* g2 = (const float*)d_in[9];
  const float* b2 = (const float*)d_in[10];
  float* out = (float*)d_out;

  float* wsf = (float*)d_ws;
  const size_t CHUNK = (size_t)LB * CB;  // 16384x256 = 4,194,304 floats
  float* bufA = wsf;                     // 16 MiB
  float* bufB = bufA + CHUNK;            // 16 MiB
  float* Pp = bufB + CHUNK;              // 32*8*1056 = 270,336 floats
  float* KVb = Pp + (size_t)SPLITS * HB * 1056;  // 4*8*1024 = 32,768 floats
  float* KSb = KVb + (size_t)NB * HB * DB * DB;  // 1,024 floats

  // ---- Phase 1: V full panel -> d_out; per-n K chunk + KV reduction ----
  proj_kernel<<<NLB / 64, 256, 0, stream>>>(x, Wv, out, 0);
  for (int n = 0; n < NB; ++n) {
    const size_t off = (size_t)n * CHUNK;
    proj_kernel<<<LB / 64, 256, 0, stream>>>(x + off, Wk, bufA, 1);
    kv_partial_kernel<<<dim3(HB, SPLITS), 256, 0, stream>>>(bufA, out + off, Pp);
    kv_final_kernel<<<HB, 256, 0, stream>>>(Pp, KVb + (size_t)n * HB * 1024,
                                            KSb + n * HB * 32);
  }

  // ---- Phase 2: Q full panel -> d_out (V dead); msg in-place ----
  proj_kernel<<<NLB / 64, 256, 0, stream>>>(x, Wq, out, 1);
  msg_kernel<<<NLB / 32, 256, 0, stream>>>(out, KVb, KSb);

  // ---- Phase 3: row-local tail, per 16384-row chunk ----
  for (int n = 0; n < NB; ++n) {
    const size_t off = (size_t)n * CHUNK;
    att_ln_kernel<<<LB / 64, 256, 0, stream>>>(out + off, Wm, g1, b1, bufA);
    mlp1_kernel<<<LB / 64, 256, 0, stream>>>(x + off, bufA, W1, bufB);
    mlp2_kernel<<<LB / 64, 256, 0, stream>>>(bufB, W2, g2, b2, x + off,
                                             out + off);
  }
}

// Round 4
// 543.641 us; speedup vs baseline: 2.4292x; 2.4292x over previous
//
#include <hip/hip_runtime.h>
#include <hip/hip_bf16.h>
#include <math.h>

#define NB 4
#define LB 16384
#define CB 256
#define HB 8
#define DB 32
#define NLB (NB * LB)
#define SPLITS 32
#define SPLIT_ROWS (LB / SPLITS)  // 512

typedef unsigned short ushort_t;
typedef __attribute__((ext_vector_type(8))) short bf16x8;
typedef __attribute__((ext_vector_type(4))) float f32x4;

__device__ __forceinline__ ushort_t f2b(float f) {
  union { __hip_bfloat16 h; ushort_t u; } cv;
  cv.h = __float2bfloat16(f);
  return cv.u;
}
__device__ __forceinline__ float b2f(ushort_t u) {
  union { __hip_bfloat16 h; ushort_t u; } cv;
  cv.u = u;
  return __bfloat162float(cv.h);
}

// ---------------------------------------------------------------------------
// MFMA GEMM core: 64x256 tile per 256-thread (4-wave) block, K=256, BK=32.
// A row-major [rows,256] (f32 or bf16, caller pre-offset to row0), WT is the
// TRANSPOSED weight [256 cols][wt_stride k] bf16 -> both frags read 16B
// K-contiguous. LDS tiles swizzled (slot ^ (row&3)) on write AND read.
// Wave w owns cols [64w,64w+64); frags: acc[m][nn] covers rows 16m..+15,
// cols 64w+16nn..+15. Layouts per learn_hip m89:
//   A: lane holds A[l&15][8*(l>>4)+i] ; B: WT row c=l&15 -> B[k][c]
//   C: row = 4*(l>>4)+reg, col = l&15.
// ---------------------------------------------------------------------------
__device__ __forceinline__ void gemm_core(const void* A, int a_f32,
                                          const ushort_t* __restrict__ WT,
                                          int wt_stride, short* lds,
                                          f32x4 acc[4][4]) {
  const int t = threadIdx.x;
  const int lane = t & 63, w = t >> 6, q = lane >> 4, lr = lane & 15;
  short* As = lds;            // 64 rows * 32 k
  short* Bs = lds + 64 * 32;  // 256 rows * 32 k
  for (int ks = 0; ks < 8; ++ks) {
    const int k0 = ks * 32;
    __syncthreads();
    {  // stage A: thread -> (row r = t>>2, k-slot s = t&3), 8 bf16 = 16B
      int r = t >> 2, s = t & 3;
      int si = r * 32 + (((s ^ (r & 3))) << 3);
      if (a_f32) {
        const float* Af = (const float*)A + (size_t)r * 256 + k0 + 8 * s;
        float4 fa = *(const float4*)Af;
        float4 fb = *(const float4*)(Af + 4);
        ushort_t tmp[8] = {f2b(fa.x), f2b(fa.y), f2b(fa.z), f2b(fa.w),
                           f2b(fb.x), f2b(fb.y), f2b(fb.z), f2b(fb.w)};
        *(uint4*)&As[si] = *(const uint4*)tmp;
      } else {
        const ushort_t* Ab = (const ushort_t*)A + (size_t)r * 256 + k0 + 8 * s;
        *(uint4*)&As[si] = *(const uint4*)Ab;
      }
    }
    #pragma unroll
    for (int j2 = 0; j2 < 4; ++j2) {  // stage B: 256 rows x 4 slots
      int idx = t + 256 * j2;
      int r = idx >> 2, s = idx & 3;
      const ushort_t* src = WT + (size_t)r * wt_stride + k0 + 8 * s;
      int si = r * 32 + (((s ^ (r & 3))) << 3);
      *(uint4*)&Bs[si] = *(const uint4*)src;
    }
    __syncthreads();
    bf16x8 af[4], bf[4];
    #pragma unroll
    for (int m = 0; m < 4; ++m) {
      int r = 16 * m + lr;
      af[m] = *(const bf16x8*)&As[r * 32 + ((q ^ (r & 3)) << 3)];
    }
    #pragma unroll
    for (int nn = 0; nn < 4; ++nn) {
      int c = 64 * w + 16 * nn + lr;
      bf[nn] = *(const bf16x8*)&Bs[c * 32 + ((q ^ (c & 3)) << 3)];
    }
    #pragma unroll
    for (int m = 0; m < 4; ++m)
      #pragma unroll
      for (int nn = 0; nn < 4; ++nn)
        acc[m][nn] = __builtin_amdgcn_mfma_f32_16x16x32_bf16(af[m], bf[nn],
                                                             acc[m][nn], 0, 0, 0);
  }
}

// ---------------------------------------------------------------------------
// Projection: Out = [phi](A @ W).  AF32: A is fp32; PHI: elu+1; OF32: out fp32.
// ---------------------------------------------------------------------------
template <int AF32, int PHI, int OF32>
__global__ __launch_bounds__(256) void proj_mfma(const void* A,
                                                 const ushort_t* __restrict__ WT,
                                                 void* Out) {
  __shared__ short lds[320 * 32];
  const int row0 = blockIdx.x * 64;
  const void* Ab = AF32 ? (const void*)((const float*)A + (size_t)row0 * 256)
                        : (const void*)((const ushort_t*)A + (size_t)row0 * 256);
  f32x4 acc[4][4];
  #pragma unroll
  for (int m = 0; m < 4; ++m)
    #pragma unroll
    for (int n = 0; n < 4; ++n) acc[m][n] = 0.0f;
  gemm_core(Ab, AF32, WT, 256, lds, acc);
  const int lane = threadIdx.x & 63, w = threadIdx.x >> 6;
  const int q = lane >> 4, lr = lane & 15;
  #pragma unroll
  for (int m = 0; m < 4; ++m)
    #pragma unroll
    for (int nn = 0; nn < 4; ++nn) {
      int col = 64 * w + 16 * nn + lr;
      #pragma unroll
      for (int reg = 0; reg < 4; ++reg) {
        int row = row0 + 16 * m + 4 * q + reg;
        float v = acc[m][nn][reg];
        if (PHI) v = (v > 0.f) ? v + 1.f : __expf(v);
        if (OF32)
          ((float*)Out)[(size_t)row * 256 + col] = v;
        else
          ((ushort_t*)Out)[(size_t)row * 256 + col] = f2b(v);
      }
    }
}

// ---------------------------------------------------------------------------
// GEMM + LayerNorm epilogue. A bf16. RESID=0: out bf16 (m1). RESID=1: out =
// x + LN(...) fp32. Full 256-wide rows span 4 waves -> LDS cross-wave reduce.
// ---------------------------------------------------------------------------
template <int RESID>
__global__ __launch_bounds__(256) void gemmln_mfma(
    const ushort_t* __restrict__ A, const ushort_t* __restrict__ WT,
    const float* __restrict__ g, const float* __restrict__ bvec,
    const float* __restrict__ resid, void* Out) {
  __shared__ short lds[320 * 32];
  __shared__ float p1[64][4], p2[64][4], mus[64], rns[64];
  const int row0 = blockIdx.x * 64;
  f32x4 acc[4][4];
  #pragma unroll
  for (int m = 0; m < 4; ++m)
    #pragma unroll
    for (int n = 0; n < 4; ++n) acc[m][n] = 0.0f;
  gemm_core(A + (size_t)row0 * 256, 0, WT, 256, lds, acc);
  const int t = threadIdx.x;
  const int lane = t & 63, w = t >> 6, q = lane >> 4, lr = lane & 15;
  #pragma unroll
  for (int m = 0; m < 4; ++m)
    #pragma unroll
    for (int reg = 0; reg < 4; ++reg) {
      float s1 = 0.f, s2 = 0.f;
      #pragma unroll
      for (int nn = 0; nn < 4; ++nn) {
        float v = acc[m][nn][reg];
        s1 += v;
        s2 += v * v;
      }
      #pragma unroll
      for (int msk = 8; msk >= 1; msk >>= 1) {
        s1 += __shfl_xor(s1, msk);
        s2 += __shfl_xor(s2, msk);
      }
      if (lr == 0) {
        p1[16 * m + 4 * q + reg][w] = s1;
        p2[16 * m + 4 * q + reg][w] = s2;
      }
    }
  __syncthreads();
  if (t < 64) {
    float a = 0.f, b = 0.f;
    #pragma unroll
    for (int ww = 0; ww < 4; ++ww) {
      a += p1[t][ww];
      b += p2[t][ww];
    }
    float mu = a * (1.f / 256.f);
    float var = b * (1.f / 256.f) - mu * mu;
    mus[t] = mu;
    rns[t] = rsqrtf(var + 1e-5f);
  }
  __syncthreads();
  float gv[4], bv[4];
  #pragma unroll
  for (int nn = 0; nn < 4; ++nn) {
    int col = 64 * w + 16 * nn + lr;
    gv[nn] = g[col];
    bv[nn] = bvec[col];
  }
  #pragma unroll
  for (int m = 0; m < 4; ++m)
    #pragma unroll
    for (int nn = 0; nn < 4; ++nn) {
      int col = 64 * w + 16 * nn + lr;
      #pragma unroll
      for (int reg = 0; reg < 4; ++reg) {
        int rl = 16 * m + 4 * q + reg;
        int row = row0 + rl;
        float v = (acc[m][nn][reg] - mus[rl]) * rns[rl] * gv[nn] + bv[nn];
        if (RESID) {
          v += resid[(size_t)row * 256 + col];
          ((float*)Out)[(size_t)row * 256 + col] = v;
        } else {
          ((ushort_t*)Out)[(size_t)row * 256 + col] = f2b(v);
        }
      }
    }
}

// ---------------------------------------------------------------------------
// MLP1: h = relu(x @ W1[:256] + m1 @ W1[256:]) -> bf16
// ---------------------------------------------------------------------------
__global__ __launch_bounds__(256) void mlp1_mfma(const float* __restrict__ x,
                                                 const ushort_t* __restrict__ m1,
                                                 const ushort_t* __restrict__ W1T,
                                                 ushort_t* __restrict__ H) {
  __shared__ short lds[320 * 32];
  const int row0 = blockIdx.x * 64;
  f32x4 acc[4][4];
  #pragma unroll
  for (int m = 0; m < 4; ++m)
    #pragma unroll
    for (int n = 0; n < 4; ++n) acc[m][n] = 0.0f;
  gemm_core(x + (size_t)row0 * 256, 1, W1T, 512, lds, acc);
  gemm_core(m1 + (size_t)row0 * 256, 0, W1T + 256, 512, lds, acc);
  const int lane = threadIdx.x & 63, w = threadIdx.x >> 6;
  const int q = lane >> 4, lr = lane & 15;
  #pragma unroll
  for (int m = 0; m < 4; ++m)
    #pragma unroll
    for (int nn = 0; nn < 4; ++nn) {
      int col = 64 * w + 16 * nn + lr;
      #pragma unroll
      for (int reg = 0; reg < 4; ++reg) {
        int row = row0 + 16 * m + 4 * q + reg;
        H[(size_t)row * 256 + col] = f2b(fmaxf(acc[m][nn][reg], 0.f));
      }
    }
}

// ---------------------------------------------------------------------------
// Weight transpose+convert: W[K][N] f32 -> WT[N][K] bf16. grid (N/64, K/64).
// ---------------------------------------------------------------------------
__global__ __launch_bounds__(256) void wtrans_kernel(const float* __restrict__ W,
                                                     ushort_t* __restrict__ WT,
                                                     int K, int N) {
  __shared__ float tile[64][65];
  const int t = threadIdx.x;
  const int bx = blockIdx.x, by = blockIdx.y;
  for (int i = t; i < 4096; i += 256) {
    int r = i >> 6, c = i & 63;
    tile[r][c] = W[(size_t)(by * 64 + r) * N + bx * 64 + c];
  }
  __syncthreads();
  for (int i = t; i < 4096; i += 256) {
    int r = i >> 6, c = i & 63;
    WT[(size_t)(bx * 64 + r) * K + by * 64 + c] = f2b(tile[c][r]);
  }
}

// ---------------------------------------------------------------------------
// KV partial: K bf16 panel (one n), V fp32 panel (one n). fp32 math.
// grid = (H=8, SPLITS=32).
// ---------------------------------------------------------------------------
__global__ __launch_bounds__(256) void kv_partial_kernel(
    const ushort_t* __restrict__ K, const float* __restrict__ V,
    float* __restrict__ Pp) {
  __shared__ float Ksh[64][32];
  __shared__ float Vsh[64][32];
  const int h = blockIdx.x;
  const int l0 = blockIdx.y * SPLIT_ROWS;
  const int t = threadIdx.x;
  const int d = t >> 3, vg = t & 7;
  float acc[4] = {0.f, 0.f, 0.f, 0.f};
  float ksacc = 0.f;
  for (int tile = 0; tile < SPLIT_ROWS / 64; ++tile) {
    __syncthreads();
    {  // K: 64x32 bf16 = one uint4 (8 vals) per thread
      int rr = t >> 2, c8 = t & 3;
      const ushort_t* src =
          K + (size_t)(l0 + tile * 64 + rr) * 256 + h * 32 + 8 * c8;
      uint4 raw = *(const uint4*)src;
      const ushort_t* pr = (const ushort_t*)&raw;
      #pragma unroll
      for (int e = 0; e < 8; ++e) Ksh[rr][8 * c8 + e] = b2f(pr[e]);
    }
    #pragma unroll
    for (int r2 = 0; r2 < 2; ++r2) {  // V: 64x32 f32 = 2 float4 per thread
      int fi = t + 256 * r2;
      int rr = fi >> 3, c4 = fi & 7;
      *(float4*)&Vsh[rr][4 * c4] =
          *(const float4*)&V[(size_t)(l0 + tile * 64 + rr) * 256 + h * 32 + 4 * c4];
    }
    __syncthreads();
    for (int r = 0; r < 64; ++r) {
      float kv = Ksh[r][d];
      if (vg == 0) ksacc += kv;
      #pragma unroll
      for (int qq = 0; qq < 4; ++qq)
        acc[qq] = fmaf(kv, Vsh[r][vg * 4 + qq], acc[qq]);
    }
  }
  float* rec = Pp + (size_t)(blockIdx.y * HB + h) * 1056;
  #pragma unroll
  for (int qq = 0; qq < 4; ++qq) rec[d * 32 + vg * 4 + qq] = acc[qq];
  if (vg == 0) rec[1024 + d] = ksacc;
}

__global__ __launch_bounds__(256) void kv_final_kernel(
    const float* __restrict__ Pp, float* __restrict__ KVn,
    float* __restrict__ KSn) {
  const int h = blockIdx.x;
  const int t = threadIdx.x;
  for (int i = t; i < 1056; i += 256) {
    float s = 0.f;
    for (int sp = 0; sp < SPLITS; ++sp) s += Pp[(size_t)(sp * HB + h) * 1056 + i];
    if (i < 1024)
      KVn[(size_t)h * 1024 + i] = s;
    else
      KSn[h * 32 + (i - 1024)] = s;
  }
}

// ---------------------------------------------------------------------------
// msg in-place on bf16 Q panel: msg = (Q.KV)/(Q.Ksum+eps) (the /L,*L cancel).
// ---------------------------------------------------------------------------
__global__ __launch_bounds__(256) void msg_kernel(ushort_t* __restrict__ QM,
                                                  const float* __restrict__ KV,
                                                  const float* __restrict__ KS) {
  __shared__ float Qs[32][256];
  __shared__ float kvs[8][32][32];
  __shared__ float ks[8][32];
  __shared__ float zs[32][8];
  const int t = threadIdx.x;
  const int row0 = blockIdx.x * 32;
  const int n = row0 >> 14;  // L = 16384
  #pragma unroll
  for (int j = 0; j < 4; ++j) {
    int fi = t + 256 * j;
    int rr = fi >> 5, g8 = fi & 31;
    const ushort_t* src = QM + (size_t)(row0 + rr) * 256 + 8 * g8;
    uint4 raw = *(const uint4*)src;
    const ushort_t* pr = (const ushort_t*)&raw;
    #pragma unroll
    for (int e = 0; e < 8; ++e) Qs[rr][8 * g8 + e] = b2f(pr[e]);
  }
  const float* KVn = KV + (size_t)n * (HB * DB * DB);
  #pragma unroll
  for (int r = 0; r < 8; ++r) {
    int fi = t + 256 * r;
    ((float4*)kvs)[fi] = ((const float4*)KVn)[fi];
  }
  ((float*)ks)[t] = KS[n * 256 + t];
  __syncthreads();
  {
    int l = t >> 3, h = t & 7;
    float dsum = 0.f;
    #pragma unroll
    for (int dd = 0; dd < 32; ++dd)
      dsum = fmaf(Qs[l][h * 32 + dd], ks[h][dd], dsum);
    zs[l][h] = 1.0f / (dsum + 1e-6f);
  }
  __syncthreads();
  const int c = t, h = c >> 5, v = c & 31;
  for (int l = 0; l < 32; ++l) {
    float s = 0.f;
    #pragma unroll
    for (int dd = 0; dd < 32; ++dd)
      s = fmaf(Qs[l][h * 32 + dd], kvs[h][dd][v], s);
    QM[(size_t)(row0 + l) * 256 + c] = f2b(s * zs[l][h]);
  }
}

// ---------------------------------------------------------------------------
// ws layout (~34 MiB, well under the proven-working budget):
//   H     : 32 MiB bf16 [65536][256]  (kv phase: bufK 8 MiB at H)
//   Pp    : 1.03 MiB ; KVb 128 KiB ; KSb 4 KiB
//   WqT,WkT,WvT,WmT,W2T: 128 KiB each ; W1T: 256 KiB   (bf16, transposed)
// d_out time-shared: V fp32 full -> Q/msg/m1 bf16 chain (upper 32 MiB) ->
// final fp32 out. Every word written before read; no atomics/memsets.
// ---------------------------------------------------------------------------
extern "C" void kernel_launch(void* const* d_in, const int* in_sizes, int n_in,
                              void* d_out, int out_size, void* d_ws,
                              size_t ws_size, hipStream_t stream) {
  const float* x = (const float*)d_in[0];
  const float* Wq = (const float*)d_in[1];
  const float* Wk = (const float*)d_in[2];
  const float* Wv = (const float*)d_in[3];
  const float* Wm = (const float*)d_in[4];
  const float* W1 = (const float*)d_in[5];
  const float* W2 = (const float*)d_in[6];
  const float* g1 = (const float*)d_in[7];
  const float* b1 = (const float*)d_in[8];
  const float* g2 = (const float*)d_in[9];
  const float* b2 = (const float*)d_in[10];
  float* out = (float*)d_out;

  const size_t PE = (size_t)NLB * CB;  // elements per panel
  char* wsb = (char*)d_ws;
  ushort_t* H = (ushort_t*)wsb;                       // 32 MiB
  ushort_t* bufK = H;                                 // 8 MiB (kv phase only)
  float* Pp = (float*)(wsb + PE * 2);                 // 1.03 MiB
  float* KVb = Pp + (size_t)SPLITS * HB * 1056;       // 128 KiB
  float* KSb = KVb + (size_t)NB * HB * DB * DB;       // 4 KiB
  ushort_t* WqT = (ushort_t*)(KSb + NB * HB * DB);
  ushort_t* WkT = WqT + 256 * 256;
  ushort_t* WvT = WkT + 256 * 256;
  ushort_t* WmT = WvT + 256 * 256;
  ushort_t* W2T = WmT + 256 * 256;
  ushort_t* W1T = W2T + 256 * 256;  // [256][512]

  // bf16 panel chain lives in the upper half of d_out
  ushort_t* panelB = (ushort_t*)((char*)d_out + PE * 2);

  // 0) weights -> transposed bf16
  wtrans_kernel<<<dim3(4, 4), 256, 0, stream>>>(Wq, WqT, 256, 256);
  wtrans_kernel<<<dim3(4, 4), 256, 0, stream>>>(Wk, WkT, 256, 256);
  wtrans_kernel<<<dim3(4, 4), 256, 0, stream>>>(Wv, WvT, 256, 256);
  wtrans_kernel<<<dim3(4, 4), 256, 0, stream>>>(Wm, WmT, 256, 256);
  wtrans_kernel<<<dim3(4, 4), 256, 0, stream>>>(W2, W2T, 256, 256);
  wtrans_kernel<<<dim3(4, 8), 256, 0, stream>>>(W1, W1T, 512, 256);

  // 1) V = x@Wv fp32 full panel -> d_out (scratch)
  proj_mfma<1, 0, 1><<<NLB / 64, 256, 0, stream>>>(x, WvT, out);
  // 2) per-n: K = phi(x@Wk) bf16 -> bufK; KV/Ksum reduction (fp32)
  for (int n = 0; n < NB; ++n) {
    const size_t off = (size_t)n * LB * CB;
    proj_mfma<1, 1, 0><<<LB / 64, 256, 0, stream>>>(x + off, WkT, bufK);
    kv_partial_kernel<<<dim3(HB, SPLITS), 256, 0, stream>>>(bufK, (float*)out + off, Pp);
    kv_final_kernel<<<HB, 256, 0, stream>>>(Pp, KVb + (size_t)n * HB * 1024,
                                            KSb + n * HB * 32);
  }
  // 3) Q = phi(x@Wq) bf16 -> panelB (V dead); msg in-place
  proj_mfma<1, 1, 0><<<NLB / 64, 256, 0, stream>>>(x, WqT, panelB);
  msg_kernel<<<NLB / 32, 256, 0, stream>>>(panelB, KVb, KSb);
  // 4) m1 = LN(msg@Wm) bf16, in-place on panelB (row-local)
  gemmln_mfma<0><<<NLB / 64, 256, 0, stream>>>(panelB, WmT, g1, b1, nullptr,
                                               panelB);
  // 5) h = relu(x@W1a + m1@W1b) bf16 -> H (ws)
  mlp1_mfma<<<NLB / 64, 256, 0, stream>>>(x, panelB, W1T, H);
  // 6) out = x + LN(h@W2) fp32 -> all of d_out
  gemmln_mfma<1><<<NLB / 64, 256, 0, stream>>>(H, W2T, g2, b2, x, out);
}

// Round 5
// 384.386 us; speedup vs baseline: 3.4356x; 1.4143x over previous
//
#include <hip/hip_runtime.h>
#include <hip/hip_bf16.h>
#include <math.h>

#define NB 4
#define LB 16384
#define CB 256
#define HB 8
#define DB 32
#define NLB (NB * LB)
#define SPLITS 32
#define SPLIT_ROWS (LB / SPLITS)  // 512

typedef unsigned short ushort_t;
typedef __attribute__((ext_vector_type(8))) short bf16x8;
typedef __attribute__((ext_vector_type(4))) float f32x4;

__device__ __forceinline__ ushort_t f2b(float f) {
  union { __hip_bfloat16 h; ushort_t u; } cv;
  cv.h = __float2bfloat16(f);
  return cv.u;
}
__device__ __forceinline__ float b2f(ushort_t u) {
  union { __hip_bfloat16 h; ushort_t u; } cv;
  cv.u = u;
  return __bfloat162float(cv.h);
}

// ---------------------------------------------------------------------------
// MFMA GEMM core v2: 128x256 tile, 512 threads (8 waves: wr=w>>2, wc=w&3),
// BK=64 (nk k-steps of 64). A row-major [*,strideA] (fp32 or bf16), WT is
// transposed bf16 weight [256 out-cols][strideB k]. LDS 8-deep XOR swizzle
// (slot ^ (row&7), 16B slots) -> ds_read_b128 2-way conflict = free (m136).
// Fragment layouts (verified by round-4 pass, per learn_hip m89):
//   A frag: lane lr = row-within-16, q = k-slot (8 elems);  B frag: lane lr =
//   out-col, q = k-slot;  C: row = 4q+reg, col = lr.
// ---------------------------------------------------------------------------
template <int AF32>
__device__ __forceinline__ void gemm_core2(const void* A, int strideA,
                                           const ushort_t* __restrict__ WT,
                                           int strideB, short* As, short* Bs,
                                           f32x4 acc[4][4], int nk) {
  const int t = threadIdx.x;
  const int lane = t & 63;
  const int w = t >> 6, wr = w >> 2, wc = w & 3;
  const int q = lane >> 4, lr = lane & 15;
  for (int ks = 0; ks < nk; ++ks) {
    const int k0 = ks * 64;
    __syncthreads();
    // stage A: 128 rows x 8 slots (16B) = 1024 slots, 2 per thread
    #pragma unroll
    for (int rep = 0; rep < 2; ++rep) {
      int si = t + 512 * rep;
      int r = si >> 3, s = si & 7;
      int dst = r * 64 + ((s ^ (r & 7)) << 3);
      if (AF32) {
        const float* src = (const float*)A + (size_t)r * strideA + k0 + 8 * s;
        float4 fa = *(const float4*)src;
        float4 fb = *(const float4*)(src + 4);
        ushort_t tmp[8] = {f2b(fa.x), f2b(fa.y), f2b(fa.z), f2b(fa.w),
                           f2b(fb.x), f2b(fb.y), f2b(fb.z), f2b(fb.w)};
        *(uint4*)&As[dst] = *(const uint4*)tmp;
      } else {
        const ushort_t* src =
            (const ushort_t*)A + (size_t)r * strideA + k0 + 8 * s;
        *(uint4*)&As[dst] = *(const uint4*)src;
      }
    }
    // stage B: 256 rows x 8 slots = 2048 slots, 4 per thread
    #pragma unroll
    for (int rep = 0; rep < 4; ++rep) {
      int si = t + 512 * rep;
      int r = si >> 3, s = si & 7;
      int dst = r * 64 + ((s ^ (r & 7)) << 3);
      const ushort_t* src = WT + (size_t)r * strideB + k0 + 8 * s;
      *(uint4*)&Bs[dst] = *(const uint4*)src;
    }
    __syncthreads();
    #pragma unroll
    for (int kk = 0; kk < 2; ++kk) {
      bf16x8 af[4], bfr[4];
      const int s = 4 * kk + q;
      #pragma unroll
      for (int m = 0; m < 4; ++m) {
        int r = wr * 64 + 16 * m + lr;
        af[m] = *(const bf16x8*)&As[r * 64 + ((s ^ (r & 7)) << 3)];
      }
      #pragma unroll
      for (int nn = 0; nn < 4; ++nn) {
        int c = wc * 64 + 16 * nn + lr;
        bfr[nn] = *(const bf16x8*)&Bs[c * 64 + ((s ^ (c & 7)) << 3)];
      }
      #pragma unroll
      for (int m = 0; m < 4; ++m)
        #pragma unroll
        for (int nn = 0; nn < 4; ++nn)
          acc[m][nn] = __builtin_amdgcn_mfma_f32_16x16x32_bf16(
              af[m], bfr[nn], acc[m][nn], 0, 0, 0);
    }
  }
}

__device__ __forceinline__ void zero_acc(f32x4 acc[4][4]) {
  #pragma unroll
  for (int m = 0; m < 4; ++m)
    #pragma unroll
    for (int n = 0; n < 4; ++n) acc[m][n] = 0.0f;
}

// bf16 epilogue store (optional phi) for the 128x256 tile
__device__ __forceinline__ void store_bf16(f32x4 acc[4][4], ushort_t* out,
                                           int row0, int do_phi) {
  const int t = threadIdx.x;
  const int lane = t & 63, w = t >> 6, wr = w >> 2, wc = w & 3;
  const int q = lane >> 4, lr = lane & 15;
  #pragma unroll
  for (int m = 0; m < 4; ++m)
    #pragma unroll
    for (int nn = 0; nn < 4; ++nn) {
      int col = wc * 64 + 16 * nn + lr;
      #pragma unroll
      for (int reg = 0; reg < 4; ++reg) {
        int row = row0 + wr * 64 + 16 * m + 4 * q + reg;
        float v = acc[m][nn][reg];
        if (do_phi) v = (v > 0.f) ? v + 1.f : __expf(v);
        out[(size_t)row * 256 + col] = f2b(v);
      }
    }
}

// ---------------------------------------------------------------------------
// Fused QKV: per 128-row tile, loop o in {Q,K,V}; x tile stays L2-hot.
// Q -> d_out lo (bf16, phi), K -> d_out hi (bf16, phi), V -> ws (bf16).
// ---------------------------------------------------------------------------
__global__ __launch_bounds__(512) void qkv3_kernel(
    const float* __restrict__ x, const ushort_t* __restrict__ WqT,
    const ushort_t* __restrict__ WkT, const ushort_t* __restrict__ WvT,
    ushort_t* __restrict__ Qb, ushort_t* __restrict__ Kb,
    ushort_t* __restrict__ Vb) {
  __shared__ short As[128 * 64];
  __shared__ short Bs[256 * 64];
  const int row0 = blockIdx.x * 128;
  const float* Ax = x + (size_t)row0 * 256;
  f32x4 acc[4][4];

  zero_acc(acc);
  gemm_core2<1>(Ax, 256, WqT, 256, As, Bs, acc, 4);
  store_bf16(acc, Qb, row0, 1);
  zero_acc(acc);
  gemm_core2<1>(Ax, 256, WkT, 256, As, Bs, acc, 4);
  store_bf16(acc, Kb, row0, 1);
  zero_acc(acc);
  gemm_core2<1>(Ax, 256, WvT, 256, As, Bs, acc, 4);
  store_bf16(acc, Vb, row0, 0);
}

// ---------------------------------------------------------------------------
// GEMM + LayerNorm. A bf16 panel. RESID=0: out bf16 (m1). RESID=1:
// out = x + LN(...) fp32.
// ---------------------------------------------------------------------------
template <int RESID>
__global__ __launch_bounds__(512) void gemmln2(
    const ushort_t* __restrict__ A, const ushort_t* __restrict__ WT,
    const float* __restrict__ g, const float* __restrict__ bvec,
    const float* __restrict__ resid, void* Out) {
  __shared__ short As[128 * 64];
  __shared__ short Bs[256 * 64];
  __shared__ float p1[128][4], p2[128][4], mus[128], rns[128];
  const int row0 = blockIdx.x * 128;
  f32x4 acc[4][4];
  zero_acc(acc);
  gemm_core2<0>(A + (size_t)row0 * 256, 256, WT, 256, As, Bs, acc, 4);
  const int t = threadIdx.x;
  const int lane = t & 63, w = t >> 6, wr = w >> 2, wc = w & 3;
  const int q = lane >> 4, lr = lane & 15;
  #pragma unroll
  for (int m = 0; m < 4; ++m)
    #pragma unroll
    for (int reg = 0; reg < 4; ++reg) {
      float s1 = 0.f, s2 = 0.f;
      #pragma unroll
      for (int nn = 0; nn < 4; ++nn) {
        float v = acc[m][nn][reg];
        s1 += v;
        s2 += v * v;
      }
      #pragma unroll
      for (int msk = 8; msk >= 1; msk >>= 1) {
        s1 += __shfl_xor(s1, msk);
        s2 += __shfl_xor(s2, msk);
      }
      if (lr == 0) {
        int rl = wr * 64 + 16 * m + 4 * q + reg;
        p1[rl][wc] = s1;
        p2[rl][wc] = s2;
      }
    }
  __syncthreads();
  if (t < 128) {
    float a = 0.f, b = 0.f;
    #pragma unroll
    for (int ww = 0; ww < 4; ++ww) {
      a += p1[t][ww];
      b += p2[t][ww];
    }
    float mu = a * (1.f / 256.f);
    float var = b * (1.f / 256.f) - mu * mu;
    mus[t] = mu;
    rns[t] = rsqrtf(var + 1e-5f);
  }
  __syncthreads();
  #pragma unroll
  for (int m = 0; m < 4; ++m)
    #pragma unroll
    for (int nn = 0; nn < 4; ++nn) {
      int col = wc * 64 + 16 * nn + lr;
      float gv = g[col], bv = bvec[col];
      #pragma unroll
      for (int reg = 0; reg < 4; ++reg) {
        int rl = wr * 64 + 16 * m + 4 * q + reg;
        int row = row0 + rl;
        float v = (acc[m][nn][reg] - mus[rl]) * rns[rl] * gv + bv;
        if (RESID) {
          v += resid[(size_t)row * 256 + col];
          ((float*)Out)[(size_t)row * 256 + col] = v;
        } else {
          ((ushort_t*)Out)[(size_t)row * 256 + col] = f2b(v);
        }
      }
    }
}

// ---------------------------------------------------------------------------
// MLP1: h = relu(x @ W1[:256] + m1 @ W1[256:]) -> bf16
// ---------------------------------------------------------------------------
__global__ __launch_bounds__(512) void mlp1_v2(const float* __restrict__ x,
                                               const ushort_t* __restrict__ m1,
                                               const ushort_t* __restrict__ W1T,
                                               ushort_t* __restrict__ H) {
  __shared__ short As[128 * 64];
  __shared__ short Bs[256 * 64];
  const int row0 = blockIdx.x * 128;
  f32x4 acc[4][4];
  zero_acc(acc);
  gemm_core2<1>(x + (size_t)row0 * 256, 256, W1T, 512, As, Bs, acc, 4);
  gemm_core2<0>(m1 + (size_t)row0 * 256, 256, W1T + 256, 512, As, Bs, acc, 4);
  const int t = threadIdx.x;
  const int lane = t & 63, w = t >> 6, wr = w >> 2, wc = w & 3;
  const int q = lane >> 4, lr = lane & 15;
  #pragma unroll
  for (int m = 0; m < 4; ++m)
    #pragma unroll
    for (int nn = 0; nn < 4; ++nn) {
      int col = wc * 64 + 16 * nn + lr;
      #pragma unroll
      for (int reg = 0; reg < 4; ++reg) {
        int row = row0 + wr * 64 + 16 * m + 4 * q + reg;
        H[(size_t)row * 256 + col] = f2b(fmaxf(acc[m][nn][reg], 0.f));
      }
    }
}

// ---------------------------------------------------------------------------
// Weight transpose+convert: W[K][N] f32 -> WT[N][K] bf16. grid (N/64, K/64).
// ---------------------------------------------------------------------------
__global__ __launch_bounds__(256) void wtrans_kernel(const float* __restrict__ W,
                                                     ushort_t* __restrict__ WT,
                                                     int K, int N) {
  __shared__ float tile[64][65];
  const int t = threadIdx.x;
  const int bx = blockIdx.x, by = blockIdx.y;
  for (int i = t; i < 4096; i += 256) {
    int r = i >> 6, c = i & 63;
    tile[r][c] = W[(size_t)(by * 64 + r) * N + bx * 64 + c];
  }
  __syncthreads();
  for (int i = t; i < 4096; i += 256) {
    int r = i >> 6, c = i & 63;
    WT[(size_t)(bx * 64 + r) * K + by * 64 + c] = f2b(tile[c][r]);
  }
}

// ---------------------------------------------------------------------------
// KV partial: K,V bf16 full panels. grid = (NB*HB, SPLITS). fp32 math.
// ---------------------------------------------------------------------------
__global__ __launch_bounds__(256) void kv_partial_kernel(
    const ushort_t* __restrict__ K, const ushort_t* __restrict__ V,
    float* __restrict__ Pp) {
  __shared__ float Ksh[64][32];
  __shared__ float Vsh[64][32];
  const int nh = blockIdx.x;
  const int n = nh >> 3, h = nh & 7;
  const int l0 = n * LB + blockIdx.y * SPLIT_ROWS;
  const int t = threadIdx.x;
  const int d = t >> 3, vg = t & 7;
  float acc[4] = {0.f, 0.f, 0.f, 0.f};
  float ksacc = 0.f;
  for (int tile = 0; tile < SPLIT_ROWS / 64; ++tile) {
    __syncthreads();
    {
      int rr = t >> 2, c8 = t & 3;
      size_t base = (size_t)(l0 + tile * 64 + rr) * 256 + h * 32 + 8 * c8;
      uint4 kr = *(const uint4*)&K[base];
      uint4 vr = *(const uint4*)&V[base];
      const ushort_t* kp = (const ushort_t*)&kr;
      const ushort_t* vp = (const ushort_t*)&vr;
      #pragma unroll
      for (int e = 0; e < 8; ++e) {
        Ksh[rr][8 * c8 + e] = b2f(kp[e]);
        Vsh[rr][8 * c8 + e] = b2f(vp[e]);
      }
    }
    __syncthreads();
    for (int r = 0; r < 64; ++r) {
      float kv = Ksh[r][d];
      if (vg == 0) ksacc += kv;
      #pragma unroll
      for (int qq = 0; qq < 4; ++qq)
        acc[qq] = fmaf(kv, Vsh[r][vg * 4 + qq], acc[qq]);
    }
  }
  float* rec = Pp + (size_t)(blockIdx.y * (NB * HB) + nh) * 1056;
  #pragma unroll
  for (int qq = 0; qq < 4; ++qq) rec[d * 32 + vg * 4 + qq] = acc[qq];
  if (vg == 0) rec[1024 + d] = ksacc;
}

__global__ __launch_bounds__(256) void kv_final_kernel(
    const float* __restrict__ Pp, float* __restrict__ KV,
    float* __restrict__ KS) {
  const int nh = blockIdx.x;
  const int t = threadIdx.x;
  for (int i = t; i < 1056; i += 256) {
    float s = 0.f;
    for (int sp = 0; sp < SPLITS; ++sp)
      s += Pp[(size_t)(sp * (NB * HB) + nh) * 1056 + i];
    if (i < 1024)
      KV[(size_t)nh * 1024 + i] = s;
    else
      KS[nh * 32 + (i - 1024)] = s;
  }
}

// ---------------------------------------------------------------------------
// msg in-place on bf16 Q panel: msg = (Q.KV)/(Q.Ksum+eps); /L and *L cancel.
// ---------------------------------------------------------------------------
__global__ __launch_bounds__(256) void msg_kernel(ushort_t* __restrict__ QM,
                                                  const float* __restrict__ KV,
                                                  const float* __restrict__ KS) {
  __shared__ float Qs[32][256];
  __shared__ float kvs[8][32][32];
  __shared__ float ks[8][32];
  __shared__ float zs[32][8];
  const int t = threadIdx.x;
  const int row0 = blockIdx.x * 32;
  const int n = row0 >> 14;  // L = 16384
  #pragma unroll
  for (int j = 0; j < 4; ++j) {
    int fi = t + 256 * j;
    int rr = fi >> 5, g8 = fi & 31;
    uint4 raw = *(const uint4*)&QM[(size_t)(row0 + rr) * 256 + 8 * g8];
    const ushort_t* pr = (const ushort_t*)&raw;
    #pragma unroll
    for (int e = 0; e < 8; ++e) Qs[rr][8 * g8 + e] = b2f(pr[e]);
  }
  const float* KVn = KV + (size_t)n * (HB * DB * DB);
  #pragma unroll
  for (int r = 0; r < 8; ++r) {
    int fi = t + 256 * r;
    ((float4*)kvs)[fi] = ((const float4*)KVn)[fi];
  }
  ((float*)ks)[t] = KS[n * 256 + t];
  __syncthreads();
  {
    int l = t >> 3, h = t & 7;
    float dsum = 0.f;
    #pragma unroll
    for (int dd = 0; dd < 32; ++dd)
      dsum = fmaf(Qs[l][h * 32 + dd], ks[h][dd], dsum);
    zs[l][h] = 1.0f / (dsum + 1e-6f);
  }
  __syncthreads();
  const int c = t, h = c >> 5, v = c & 31;
  for (int l = 0; l < 32; ++l) {
    float s = 0.f;
    #pragma unroll
    for (int dd = 0; dd < 32; ++dd)
      s = fmaf(Qs[l][h * 32 + dd], kvs[h][dd][v], s);
    QM[(size_t)(row0 + l) * 256 + c] = f2b(s * zs[l][h]);
  }
}

// ---------------------------------------------------------------------------
// Buffers:  d_out lo = Q -> msg -> (clobbered by final out)
//           d_out hi = K -> m1  -> (clobbered by final out)
//           ws: Vb/H (32 MiB, time-shared) + Pp 4.3 MB + KV/KS + WT ~1 MB
// Every word written before read; no atomics/memsets; ~38 MB ws (proven range).
// ---------------------------------------------------------------------------
extern "C" void kernel_launch(void* const* d_in, const int* in_sizes, int n_in,
                              void* d_out, int out_size, void* d_ws,
                              size_t ws_size, hipStream_t stream) {
  const float* x = (const float*)d_in[0];
  const float* Wq = (const float*)d_in[1];
  const float* Wk = (const float*)d_in[2];
  const float* Wv = (const float*)d_in[3];
  const float* Wm = (const float*)d_in[4];
  const float* W1 = (const float*)d_in[5];
  const float* W2 = (const float*)d_in[6];
  const float* g1 = (const float*)d_in[7];
  const float* b1 = (const float*)d_in[8];
  const float* g2 = (const float*)d_in[9];
  const float* b2 = (const float*)d_in[10];
  float* out = (float*)d_out;

  const size_t PE = (size_t)NLB * CB;  // 16.7M elems
  ushort_t* Qb = (ushort_t*)d_out;                  // lower 32 MiB
  ushort_t* Kb = (ushort_t*)((char*)d_out + PE * 2);  // upper 32 MiB

  char* wsb = (char*)d_ws;
  ushort_t* Vb = (ushort_t*)wsb;  // 32 MiB (later reused as H)
  float* Pp = (float*)(wsb + PE * 2);                    // 4.3 MB
  float* KVb = Pp + (size_t)SPLITS * NB * HB * 1056;     // 128 KB
  float* KSb = KVb + (size_t)NB * HB * DB * DB;          // 4 KB
  ushort_t* WqT = (ushort_t*)(KSb + NB * HB * DB);
  ushort_t* WkT = WqT + 256 * 256;
  ushort_t* WvT = WkT + 256 * 256;
  ushort_t* WmT = WvT + 256 * 256;
  ushort_t* W2T = WmT + 256 * 256;
  ushort_t* W1T = W2T + 256 * 256;  // [256][512]

  wtrans_kernel<<<dim3(4, 4), 256, 0, stream>>>(Wq, WqT, 256, 256);
  wtrans_kernel<<<dim3(4, 4), 256, 0, stream>>>(Wk, WkT, 256, 256);
  wtrans_kernel<<<dim3(4, 4), 256, 0, stream>>>(Wv, WvT, 256, 256);
  wtrans_kernel<<<dim3(4, 4), 256, 0, stream>>>(Wm, WmT, 256, 256);
  wtrans_kernel<<<dim3(4, 4), 256, 0, stream>>>(W2, W2T, 256, 256);
  wtrans_kernel<<<dim3(4, 8), 256, 0, stream>>>(W1, W1T, 512, 256);

  qkv3_kernel<<<NLB / 128, 512, 0, stream>>>(x, WqT, WkT, WvT, Qb, Kb, Vb);
  kv_partial_kernel<<<dim3(NB * HB, SPLITS), 256, 0, stream>>>(Kb, Vb, Pp);
  kv_final_kernel<<<NB * HB, 256, 0, stream>>>(Pp, KVb, KSb);
  msg_kernel<<<NLB / 32, 256, 0, stream>>>(Qb, KVb, KSb);
  // m1 = LN(msg @ Wm) -> Kb slot (K dead)
  gemmln2<0><<<NLB / 128, 512, 0, stream>>>(Qb, WmT, g1, b1, nullptr, Kb);
  // h = relu(x@W1a + m1@W1b) -> ws (V dead)
  mlp1_v2<<<NLB / 128, 512, 0, stream>>>(x, Kb, W1T, Vb);
  // out = x + LN(h @ W2) -> full d_out (Q/msg/m1 dead)
  gemmln2<1><<<NLB / 128, 512, 0, stream>>>(Vb, W2T, g2, b2, x, out);
}